// Round 1
// baseline (516.801 us; speedup 1.0000x reference)
//
#include <hip/hip_runtime.h>

#define IN_CH 256
#define OUT_CH 64
#define SCAN_CHUNK 1024   // elements per scan block (256 threads x 4)
#define NGROUP 8          // one group per XCD (blockIdx & 7 round-robin)

// ---- bf16 helpers (RNE) ----
__device__ __forceinline__ unsigned short f2bf(float f) {
    unsigned u = __float_as_uint(f);
    u += 0x7fff + ((u >> 16) & 1);
    return (unsigned short)(u >> 16);
}
__device__ __forceinline__ float bf2f(unsigned short h) {
    return __uint_as_float((unsigned)h << 16);
}

using bfrag = __attribute__((ext_vector_type(8))) short;   // 8 bf16 (4 VGPRs)
using ffrag = __attribute__((ext_vector_type(4))) float;   // 4 fp32 acc

// ---------------------------------------------------------------------------
// MFMA dense transform: B0[n][64] = bf16(relu(feat @ W + bias))
// (unchanged from previous round — verified layouts)
// ---------------------------------------------------------------------------
__global__ __launch_bounds__(256) void gemm_mfma_kernel(
    const float* __restrict__ feat, const float* __restrict__ W,
    const float* __restrict__ bias, unsigned short* __restrict__ out, int n)
{
    __shared__ unsigned short Wl[IN_CH * OUT_CH / 8 * 8];   // 32 KB

    for (int i = threadIdx.x; i < IN_CH * OUT_CH; i += 256) {
        int k  = i >> 6;          // 0..255
        int c  = i & 63;          // 0..63
        int ks = k >> 5;
        int kq = (k >> 3) & 3;
        int j  = k & 7;
        int nt = c >> 4;
        int lc = c & 15;
        Wl[(((ks * 4 + nt) * 64) + kq * 16 + lc) * 8 + j] = f2bf(W[i]);
    }
    __syncthreads();

    const int wv   = threadIdx.x >> 6;
    const int lane = threadIdx.x & 63;
    const int quad = lane >> 4;
    const int lc   = lane & 15;

    const int arow = blockIdx.x * 64 + wv * 16 + lc;      // A-fragment row
    const int lrow = min(arow, n - 1);
    const float4* frow = (const float4*)(feat + (size_t)lrow * IN_CH);

    ffrag acc[4];
#pragma unroll
    for (int nt = 0; nt < 4; ++nt)
#pragma unroll
        for (int r = 0; r < 4; ++r) acc[nt][r] = 0.f;

#pragma unroll
    for (int ks = 0; ks < 8; ++ks) {
        const int k0 = ks * 32;
        float4 a0 = frow[(k0 >> 2) + quad * 2 + 0];
        float4 a1 = frow[(k0 >> 2) + quad * 2 + 1];
        bfrag af;
        af[0] = (short)f2bf(a0.x); af[1] = (short)f2bf(a0.y);
        af[2] = (short)f2bf(a0.z); af[3] = (short)f2bf(a0.w);
        af[4] = (short)f2bf(a1.x); af[5] = (short)f2bf(a1.y);
        af[6] = (short)f2bf(a1.z); af[7] = (short)f2bf(a1.w);
#pragma unroll
        for (int nt = 0; nt < 4; ++nt) {
            bfrag bf = *(const bfrag*)&Wl[(((ks * 4 + nt) * 64) + lane) * 8];
            acc[nt] = __builtin_amdgcn_mfma_f32_16x16x32_bf16(af, bf, acc[nt], 0, 0, 0);
        }
    }

#pragma unroll
    for (int nt = 0; nt < 4; ++nt) {
        float bv = bias[nt * 16 + lc];
#pragma unroll
        for (int r = 0; r < 4; ++r) {
            int orow = blockIdx.x * 64 + wv * 16 + quad * 4 + r;
            if (orow < n) {
                float v = fmaxf(acc[nt][r] + bv, 0.f);
                out[(size_t)orow * OUT_CH + nt * 16 + lc] = f2bf(v);
            }
        }
    }
}

// ---------------------------------------------------------------------------
// CSR build, two-level counting sort.
// Pass 0: count edges per destination-octile bucket (one read of rows).
// Pass 1: scatter edges compactly into 8 contiguous bucket regions
//         (block-aggregated reservations -> near-coalesced writes).
// Pass 2+: per-row hist + final scatter run per-bucket on the owning XCD
//         (blockIdx&7), so row atomics and spack writes are XCD-L2-local
//         with only ~2.4 MB of streaming reads per XCD (lines merge).
// ---------------------------------------------------------------------------
__global__ __launch_bounds__(256) void bucket_count_kernel(
    const int* __restrict__ rows, int* __restrict__ bucketCnt,
    int nEdges, float invRpg)
{
    __shared__ int l[NGROUP];
    const int t = threadIdx.x;
    if (t < NGROUP) l[t] = 0;
    __syncthreads();
    int cnt[NGROUP] = {0, 0, 0, 0, 0, 0, 0, 0};
    const int stride = gridDim.x * 256;
    for (int e = blockIdx.x * 256 + t; e < nEdges; e += stride) {
        int r = __builtin_nontemporal_load(rows + e);
        int b = min((int)((float)r * invRpg), NGROUP - 1);
#pragma unroll
        for (int k = 0; k < NGROUP; ++k) cnt[k] += (b == k) ? 1 : 0;
    }
#pragma unroll
    for (int k = 0; k < NGROUP; ++k)
        if (cnt[k]) atomicAdd(&l[k], cnt[k]);
    __syncthreads();
    if (t < NGROUP && l[t]) atomicAdd(&bucketCnt[t], l[t]);
}

__global__ void bucket_scan_kernel(const int* __restrict__ bucketCnt,
                                   int* __restrict__ bucketBase,
                                   int* __restrict__ bucketCursor)
{
    int run = 0;
    for (int g = 0; g < NGROUP; ++g) {
        bucketBase[g] = run;
        bucketCursor[g] = run;
        run += bucketCnt[g];
    }
    bucketBase[NGROUP] = run;
}

// one block = one 1024-edge chunk; two LDS-atomic phases (count, place)
__global__ __launch_bounds__(256) void bucket_scatter_kernel(
    const int* __restrict__ rows, const int* __restrict__ cols,
    const float* __restrict__ vals, int* __restrict__ bucketCursor,
    int* __restrict__ br, int* __restrict__ bc, float* __restrict__ bv,
    int nEdges, float invRpg)
{
    __shared__ int lbase[NGROUP];
    __shared__ int lcur[NGROUP];
    const int t  = threadIdx.x;
    const int e0 = blockIdx.x * 1024;

    int   r[4], c[4], b[4];
    float v[4];
#pragma unroll
    for (int j = 0; j < 4; ++j) {
        int e = e0 + j * 256 + t;
        bool ok = e < nEdges;
        r[j] = ok ? __builtin_nontemporal_load(rows + e) : 0;
        c[j] = ok ? __builtin_nontemporal_load(cols + e) : 0;
        v[j] = ok ? __builtin_nontemporal_load(vals + e) : 0.f;
        b[j] = ok ? min((int)((float)r[j] * invRpg), NGROUP - 1) : -1;
    }
    if (t < NGROUP) lcur[t] = 0;
    __syncthreads();
#pragma unroll
    for (int j = 0; j < 4; ++j)
        if (b[j] >= 0) atomicAdd(&lcur[b[j]], 1);
    __syncthreads();
    if (t < NGROUP) {
        lbase[t] = atomicAdd(&bucketCursor[t], lcur[t]);
        lcur[t]  = 0;
    }
    __syncthreads();
#pragma unroll
    for (int j = 0; j < 4; ++j) {
        if (b[j] >= 0) {
            int pos = lbase[b[j]] + atomicAdd(&lcur[b[j]], 1);
            br[pos] = r[j];
            bc[pos] = c[j];
            bv[pos] = v[j];
        }
    }
}

__global__ __launch_bounds__(256) void hist_bucket_kernel(
    const int* __restrict__ br, const int* __restrict__ bucketBase,
    int* __restrict__ cnt)
{
    const int g     = blockIdx.x & (NGROUP - 1);
    const int blkIn = blockIdx.x >> 3;
    const int nBlk  = gridDim.x >> 3;
    const int lo = bucketBase[g], hi = bucketBase[g + 1];
    const int stride = nBlk * 256;
    for (int e = lo + blkIn * 256 + threadIdx.x; e < hi; e += stride)
        atomicAdd(&cnt[__builtin_nontemporal_load(br + e)], 1);
}

__global__ __launch_bounds__(256) void scatter_bucket_kernel(
    const int* __restrict__ br, const int* __restrict__ bc,
    const float* __restrict__ bv, const int* __restrict__ bucketBase,
    int* __restrict__ cursor, int2* __restrict__ spack)
{
    const int g     = blockIdx.x & (NGROUP - 1);
    const int blkIn = blockIdx.x >> 3;
    const int nBlk  = gridDim.x >> 3;
    const int lo = bucketBase[g], hi = bucketBase[g + 1];
    const int stride = nBlk * 256;
    for (int e = lo + blkIn * 256 + threadIdx.x; e < hi; e += stride) {
        int   r = __builtin_nontemporal_load(br + e);
        int   c = __builtin_nontemporal_load(bc + e);
        float v = __builtin_nontemporal_load(bv + e);
        int pos = atomicAdd(&cursor[r], 1);
        spack[pos] = make_int2(c, __float_as_int(v));
    }
}

// ---------------------------------------------------------------------------
// Scan kernels (unchanged)
// ---------------------------------------------------------------------------
__global__ __launch_bounds__(256) void block_sum_kernel(
    const int* __restrict__ cnt, int* __restrict__ blockSums, int n)
{
    __shared__ int ls[256];
    int t = threadIdx.x;
    int base = blockIdx.x * SCAN_CHUNK + t * 4;
    int s = 0;
#pragma unroll
    for (int j = 0; j < 4; ++j) {
        int i = base + j;
        if (i < n) s += cnt[i];
    }
    ls[t] = s;
    __syncthreads();
    for (int off = 128; off > 0; off >>= 1) {
        if (t < off) ls[t] += ls[t + off];
        __syncthreads();
    }
    if (t == 0) blockSums[blockIdx.x] = ls[0];
}

__global__ void scan_sums_kernel(int* __restrict__ blockSums, int nb,
                                 int* __restrict__ rowptr, int n, int total)
{
    int run = 0;
    for (int i = 0; i < nb; ++i) {
        int c = blockSums[i];
        blockSums[i] = run;
        run += c;
    }
    rowptr[n] = total;
}

__global__ __launch_bounds__(256) void scan_final_kernel(
    const int* __restrict__ cnt, const int* __restrict__ blockSums,
    int* __restrict__ rowptr, int* __restrict__ cursor, int n)
{
    __shared__ int ls[256];
    int t = threadIdx.x;
    int base = blockIdx.x * SCAN_CHUNK + t * 4;
    int v0 = (base + 0 < n) ? cnt[base + 0] : 0;
    int v1 = (base + 1 < n) ? cnt[base + 1] : 0;
    int v2 = (base + 2 < n) ? cnt[base + 2] : 0;
    int v3 = (base + 3 < n) ? cnt[base + 3] : 0;
    ls[t] = v0 + v1 + v2 + v3;
    __syncthreads();
    for (int off = 1; off < 256; off <<= 1) {
        int x = (t >= off) ? ls[t - off] : 0;
        __syncthreads();
        ls[t] += x;
        __syncthreads();
    }
    int prefix = blockSums[blockIdx.x] + (t ? ls[t - 1] : 0);
    int e0 = prefix;
    int e1 = e0 + v0;
    int e2 = e1 + v1;
    int e3 = e2 + v2;
    if (base + 0 < n) { rowptr[base + 0] = e0; cursor[base + 0] = e0; }
    if (base + 1 < n) { rowptr[base + 1] = e1; cursor[base + 1] = e1; }
    if (base + 2 < n) { rowptr[base + 2] = e2; cursor[base + 2] = e2; }
    if (base + 3 < n) { rowptr[base + 3] = e3; cursor[base + 3] = e3; }
}

// ---------------------------------------------------------------------------
// CSR SpMM hop (unchanged): one wave per row, quarter-wave per edge.
// ---------------------------------------------------------------------------
template<bool DST_F32>
__global__ __launch_bounds__(256) void spmm_csr_kernel(
    const int* __restrict__ rowptr, const int2* __restrict__ spack,
    const unsigned short* __restrict__ src, void* __restrict__ dstv, int n)
{
    const int row  = blockIdx.x * 4 + (threadIdx.x >> 6);
    const int lane = threadIdx.x & 63;
    if (row >= n) return;

    const int beg = rowptr[row];
    const int end = rowptr[row + 1];
    const int sub = lane >> 4;
    const int ch  = (lane & 15) * 4;

    float4 acc0 = make_float4(0.f, 0.f, 0.f, 0.f);
    float4 acc1 = make_float4(0.f, 0.f, 0.f, 0.f);

    for (int b = beg; b < end; b += 16) {
        int e0 = b + sub;
        int e1 = b + 4 + sub;
        int e2 = b + 8 + sub;
        int e3 = b + 12 + sub;
        int2 p0 = spack[min(e0, end - 1)];
        int2 p1 = spack[min(e1, end - 1)];
        int2 p2 = spack[min(e2, end - 1)];
        int2 p3 = spack[min(e3, end - 1)];
        float v0 = (e0 < end) ? __int_as_float(p0.y) : 0.f;
        float v1 = (e1 < end) ? __int_as_float(p1.y) : 0.f;
        float v2 = (e2 < end) ? __int_as_float(p2.y) : 0.f;
        float v3 = (e3 < end) ? __int_as_float(p3.y) : 0.f;
        ushort4 s0 = *(const ushort4*)(src + ((size_t)p0.x << 6) + ch);
        ushort4 s1 = *(const ushort4*)(src + ((size_t)p1.x << 6) + ch);
        ushort4 s2 = *(const ushort4*)(src + ((size_t)p2.x << 6) + ch);
        ushort4 s3 = *(const ushort4*)(src + ((size_t)p3.x << 6) + ch);
        acc0.x = fmaf(v0, bf2f(s0.x), acc0.x);
        acc0.y = fmaf(v0, bf2f(s0.y), acc0.y);
        acc0.z = fmaf(v0, bf2f(s0.z), acc0.z);
        acc0.w = fmaf(v0, bf2f(s0.w), acc0.w);
        acc1.x = fmaf(v1, bf2f(s1.x), acc1.x);
        acc1.y = fmaf(v1, bf2f(s1.y), acc1.y);
        acc1.z = fmaf(v1, bf2f(s1.z), acc1.z);
        acc1.w = fmaf(v1, bf2f(s1.w), acc1.w);
        acc0.x = fmaf(v2, bf2f(s2.x), acc0.x);
        acc0.y = fmaf(v2, bf2f(s2.y), acc0.y);
        acc0.z = fmaf(v2, bf2f(s2.z), acc0.z);
        acc0.w = fmaf(v2, bf2f(s2.w), acc0.w);
        acc1.x = fmaf(v3, bf2f(s3.x), acc1.x);
        acc1.y = fmaf(v3, bf2f(s3.y), acc1.y);
        acc1.z = fmaf(v3, bf2f(s3.z), acc1.z);
        acc1.w = fmaf(v3, bf2f(s3.w), acc1.w);
    }

    float4 acc = make_float4(acc0.x + acc1.x, acc0.y + acc1.y,
                             acc0.z + acc1.z, acc0.w + acc1.w);

#pragma unroll
    for (int mask = 16; mask <= 32; mask <<= 1) {
        acc.x += __shfl_xor(acc.x, mask);
        acc.y += __shfl_xor(acc.y, mask);
        acc.z += __shfl_xor(acc.z, mask);
        acc.w += __shfl_xor(acc.w, mask);
    }

    if (lane < 16) {
        if constexpr (DST_F32) {
            *(float4*)((float*)dstv + ((size_t)row << 6) + ch) = acc;
        } else {
            ushort4 o;
            o.x = f2bf(acc.x);
            o.y = f2bf(acc.y);
            o.z = f2bf(acc.z);
            o.w = f2bf(acc.w);
            *(ushort4*)((unsigned short*)dstv + ((size_t)row << 6) + ch) = o;
        }
    }
}

// ---------------------------------------------------------------------------
extern "C" void kernel_launch(void* const* d_in, const int* in_sizes, int n_in,
                              void* d_out, int out_size, void* d_ws, size_t ws_size,
                              hipStream_t stream)
{
    const int*   adj  = (const int*)d_in[0];    // [2, E] int32
    const float* vals = (const float*)d_in[1];  // [E]
    const float* feat = (const float*)d_in[2];  // [N, 256]
    const float* W    = (const float*)d_in[3];  // [256, 64]
    const float* bias = (const float*)d_in[4];  // [1, 64]

    const int E = in_sizes[1];
    const int n = in_sizes[2] / IN_CH;
    const int* rows = adj;       // destination rows
    const int* cols = adj + E;   // gather sources

    // ---- workspace layout (256 B aligned regions) ----
    char* ws = (char*)d_ws;
    size_t off = 0;
    auto alloc = [&](size_t bytes) {
        void* p = ws + off;
        off += (bytes + 255) & ~(size_t)255;
        return p;
    };
    unsigned short* B0 = (unsigned short*)alloc((size_t)n * OUT_CH * sizeof(unsigned short));
    unsigned short* B1 = (unsigned short*)alloc((size_t)n * OUT_CH * sizeof(unsigned short));
    int*   rowptr    = (int*)  alloc((size_t)(n + 1) * sizeof(int));
    int*   cursor    = (int*)  alloc((size_t)n * sizeof(int));
    int2*  spack     = (int2*) alloc((size_t)E * sizeof(int2));
    int*   blockSums = (int*)  alloc(4096 * sizeof(int));
    int*   bmeta     = (int*)  alloc(32 * sizeof(int));
    int* bucketCnt    = bmeta;        // [8]
    int* bucketBase   = bmeta + 8;    // [9]
    int* bucketCursor = bmeta + 17;   // [8]

    // bucket edge arrays alias B0/B1 (dead until gemm, which is stream-ordered
    // after the CSR build): need 3*E*4 = 19.2 MB <= 2*n*64*2 = 25.6 MB.
    int*   br = (int*)B0;
    int*   bc = br + E;
    float* bv = (float*)(bc + E);

    float* out = (float*)d_out;
    const float invRpg = (float)NGROUP / (float)n;

    // ---- build CSR (two-level counting sort) ----
    hipMemsetAsync(cursor, 0, (size_t)n * sizeof(int), stream);
    hipMemsetAsync(bucketCnt, 0, NGROUP * sizeof(int), stream);

    bucket_count_kernel<<<1024, 256, 0, stream>>>(rows, bucketCnt, E, invRpg);
    bucket_scan_kernel<<<1, 1, 0, stream>>>(bucketCnt, bucketBase, bucketCursor);
    bucket_scatter_kernel<<<(E + 1023) / 1024, 256, 0, stream>>>(
        rows, cols, vals, bucketCursor, br, bc, bv, E, invRpg);
    hist_bucket_kernel<<<2048, 256, 0, stream>>>(br, bucketBase, cursor);

    const int nb = (n + SCAN_CHUNK - 1) / SCAN_CHUNK;
    block_sum_kernel<<<nb, 256, 0, stream>>>(cursor, blockSums, n);
    scan_sums_kernel<<<1, 1, 0, stream>>>(blockSums, nb, rowptr, n, E);
    scan_final_kernel<<<nb, 256, 0, stream>>>(cursor, blockSums, rowptr, cursor, n);

    scatter_bucket_kernel<<<2048, 256, 0, stream>>>(
        br, bc, bv, bucketBase, cursor, spack);

    // ---- dense transform (MFMA, bf16 output) ----
    gemm_mfma_kernel<<<(n + 63) / 64, 256, 0, stream>>>(feat, W, bias, B0, n);

    // ---- 3 SpMM hops: B0 -> B1 -> B0 -> out(fp32) ----
    const int hblocks = (n + 3) / 4;
    spmm_csr_kernel<false><<<hblocks, 256, 0, stream>>>(rowptr, spack, B0, B1, n);
    spmm_csr_kernel<false><<<hblocks, 256, 0, stream>>>(rowptr, spack, B1, B0, n);
    spmm_csr_kernel<true><<<hblocks, 256, 0, stream>>>(rowptr, spack, B0, out, n);
}

// Round 2
// 396.126 us; speedup vs baseline: 1.3046x; 1.3046x over previous
//
#include <hip/hip_runtime.h>

#define IN_CH 256
#define OUT_CH 64
#define NFMAX 512          // max fine buckets (n <= 131072)
#define RPB 256            // rows per fine bucket (b = r >> 8)
#define CHUNK 6144         // edges per fine_scatter block (24 per thread)
#define CAP 8192           // staged edges per bucket_sort window (64 KB LDS)

// ---- bf16 helpers (RNE) ----
__device__ __forceinline__ unsigned short f2bf(float f) {
    unsigned u = __float_as_uint(f);
    u += 0x7fff + ((u >> 16) & 1);
    return (unsigned short)(u >> 16);
}
__device__ __forceinline__ float bf2f(unsigned short h) {
    return __uint_as_float((unsigned)h << 16);
}

struct Edge12 { int r; int c; float v; };   // packed 12 B edge record

using bfrag = __attribute__((ext_vector_type(8))) short;   // 8 bf16 (4 VGPRs)
using ffrag = __attribute__((ext_vector_type(4))) float;   // 4 fp32 acc

// ---------------------------------------------------------------------------
// MFMA dense transform: B0[n][64] = bf16(relu(feat @ W + bias))  (unchanged)
// ---------------------------------------------------------------------------
__global__ __launch_bounds__(256) void gemm_mfma_kernel(
    const float* __restrict__ feat, const float* __restrict__ W,
    const float* __restrict__ bias, unsigned short* __restrict__ out, int n)
{
    __shared__ unsigned short Wl[IN_CH * OUT_CH / 8 * 8];   // 32 KB

    for (int i = threadIdx.x; i < IN_CH * OUT_CH; i += 256) {
        int k  = i >> 6;
        int c  = i & 63;
        int ks = k >> 5;
        int kq = (k >> 3) & 3;
        int j  = k & 7;
        int nt = c >> 4;
        int lc = c & 15;
        Wl[(((ks * 4 + nt) * 64) + kq * 16 + lc) * 8 + j] = f2bf(W[i]);
    }
    __syncthreads();

    const int wv   = threadIdx.x >> 6;
    const int lane = threadIdx.x & 63;
    const int quad = lane >> 4;
    const int lc   = lane & 15;

    const int arow = blockIdx.x * 64 + wv * 16 + lc;
    const int lrow = min(arow, n - 1);
    const float4* frow = (const float4*)(feat + (size_t)lrow * IN_CH);

    ffrag acc[4];
#pragma unroll
    for (int nt = 0; nt < 4; ++nt)
#pragma unroll
        for (int r = 0; r < 4; ++r) acc[nt][r] = 0.f;

#pragma unroll
    for (int ks = 0; ks < 8; ++ks) {
        const int k0 = ks * 32;
        float4 a0 = frow[(k0 >> 2) + quad * 2 + 0];
        float4 a1 = frow[(k0 >> 2) + quad * 2 + 1];
        bfrag af;
        af[0] = (short)f2bf(a0.x); af[1] = (short)f2bf(a0.y);
        af[2] = (short)f2bf(a0.z); af[3] = (short)f2bf(a0.w);
        af[4] = (short)f2bf(a1.x); af[5] = (short)f2bf(a1.y);
        af[6] = (short)f2bf(a1.z); af[7] = (short)f2bf(a1.w);
#pragma unroll
        for (int nt = 0; nt < 4; ++nt) {
            bfrag bf = *(const bfrag*)&Wl[(((ks * 4 + nt) * 64) + lane) * 8];
            acc[nt] = __builtin_amdgcn_mfma_f32_16x16x32_bf16(af, bf, acc[nt], 0, 0, 0);
        }
    }

#pragma unroll
    for (int nt = 0; nt < 4; ++nt) {
        float bv = bias[nt * 16 + lc];
#pragma unroll
        for (int r = 0; r < 4; ++r) {
            int orow = blockIdx.x * 64 + wv * 16 + quad * 4 + r;
            if (orow < n) {
                float v = fmaxf(acc[nt][r] + bv, 0.f);
                out[(size_t)orow * OUT_CH + nt * 16 + lc] = f2bf(v);
            }
        }
    }
}

// ---------------------------------------------------------------------------
// CSR build v3: LDS-staged counting sort. All global writes are contiguous
// segments (the L2 does not merge partial-line random stores -> round-1's
// 5.7x write amplification; contiguity at store time is the only fix).
// ---------------------------------------------------------------------------

// Pass 1: per-fine-bucket histogram (one streaming read of rows)
__global__ __launch_bounds__(256) void fine_count_kernel(
    const int* __restrict__ rows, int* __restrict__ fineCnt,
    int nEdges, int nfine)
{
    __shared__ int h[NFMAX];
    const int t = threadIdx.x;
    for (int i = t; i < nfine; i += 256) h[i] = 0;
    __syncthreads();
    const int stride = gridDim.x * 256;
    for (int e = blockIdx.x * 256 + t; e < nEdges; e += stride)
        atomicAdd(&h[__builtin_nontemporal_load(rows + e) >> 8], 1);
    __syncthreads();
    for (int i = t; i < nfine; i += 256) {
        int v = h[i];
        if (v) atomicAdd(&fineCnt[i], v);
    }
}

// Pass 2: parallel exclusive scan of fine counts (1 block). Replaces the
// serial scan_sums kernel. Also seeds flushCursor and writes rowptr[n].
__global__ __launch_bounds__(256) void fine_scan_kernel(
    const int* __restrict__ fineCnt, int* __restrict__ fineBase,
    int* __restrict__ flushCursor, int* __restrict__ rowptr,
    int n, int nfine, int E)
{
    __shared__ int tmp[256];
    const int t = threadIdx.x;
    int a = (2 * t     < nfine) ? fineCnt[2 * t]     : 0;
    int b = (2 * t + 1 < nfine) ? fineCnt[2 * t + 1] : 0;
    tmp[t] = a + b;
    __syncthreads();
    for (int off = 1; off < 256; off <<= 1) {
        int x = (t >= off) ? tmp[t - off] : 0;
        __syncthreads();
        tmp[t] += x;
        __syncthreads();
    }
    int excl = tmp[t] - (a + b);
    if (2 * t < nfine)     { fineBase[2 * t]     = excl;     flushCursor[2 * t]     = excl;     }
    if (2 * t + 1 < nfine) { fineBase[2 * t + 1] = excl + a; flushCursor[2 * t + 1] = excl + a; }
    if (t == 0) { fineBase[nfine] = E; rowptr[n] = E; }
}

// Pass 3: LDS-binned scatter into fine-bucket-contiguous 12 B edge records.
// Per block: 6144 edges binned in LDS, one global atomic reservation per
// touched bucket, then flush as contiguous per-bucket segments (~190 B).
__global__ __launch_bounds__(256) void fine_scatter_kernel(
    const int* __restrict__ rows, const int* __restrict__ cols,
    const float* __restrict__ vals, int* __restrict__ flushCursor,
    Edge12* __restrict__ eb, int nEdges, int nfine)
{
    __shared__ int hist[NFMAX];
    __shared__ int lofs[NFMAX];
    __shared__ int gpos[NFMAX];
    __shared__ int cur[NFMAX];
    __shared__ int scanTmp[256];
    __shared__ int   sr[CHUNK];
    __shared__ int   sc[CHUNK];
    __shared__ float sv[CHUNK];

    const int t  = threadIdx.x;
    const int e0 = blockIdx.x * CHUNK;
    const int cnt_in = min(CHUNK, nEdges - e0);

    for (int i = t; i < nfine; i += 256) hist[i] = 0;
    __syncthreads();

    int   lr[CHUNK / 256];
    int   lc[CHUNK / 256];
    float lv[CHUNK / 256];
#pragma unroll
    for (int j = 0; j < CHUNK / 256; ++j) {
        int i = j * 256 + t;
        if (i < cnt_in) {
            lr[j] = __builtin_nontemporal_load(rows + e0 + i);
            lc[j] = __builtin_nontemporal_load(cols + e0 + i);
            lv[j] = __builtin_nontemporal_load(vals + e0 + i);
            atomicAdd(&hist[lr[j] >> 8], 1);
        } else {
            lr[j] = -1;
        }
    }
    __syncthreads();

    // exclusive scan of hist (nfine <= 512) via 2-per-thread Hillis-Steele
    int a  = (2 * t     < nfine) ? hist[2 * t]     : 0;
    int b2 = (2 * t + 1 < nfine) ? hist[2 * t + 1] : 0;
    scanTmp[t] = a + b2;
    __syncthreads();
    for (int off = 1; off < 256; off <<= 1) {
        int x = (t >= off) ? scanTmp[t - off] : 0;
        __syncthreads();
        scanTmp[t] += x;
        __syncthreads();
    }
    int excl = scanTmp[t] - (a + b2);
    if (2 * t < nfine)     lofs[2 * t]     = excl;
    if (2 * t + 1 < nfine) lofs[2 * t + 1] = excl + a;
    __syncthreads();

    // global segment reservations + staging cursors
    for (int i = t; i < nfine; i += 256) {
        int h = hist[i];
        gpos[i] = h ? atomicAdd(&flushCursor[i], h) : 0;
        cur[i]  = lofs[i];
    }
    __syncthreads();

    // place edges into LDS staging grouped by bucket
#pragma unroll
    for (int j = 0; j < CHUNK / 256; ++j) {
        if (lr[j] >= 0) {
            int bk = lr[j] >> 8;
            int p  = atomicAdd(&cur[bk], 1);
            sr[p] = lr[j];
            sc[p] = lc[j];
            sv[p] = lv[j];
        }
    }
    __syncthreads();

    // flush: consecutive staging indices -> contiguous global segments
    for (int i = t; i < cnt_in; i += 256) {
        int bk = sr[i] >> 8;
        int p  = gpos[bk] + (i - lofs[bk]);
        eb[p].r = sr[i];
        eb[p].c = sc[i];
        eb[p].v = sv[i];
    }
}

// Pass 4: one block per fine bucket. LDS per-row hist -> scan -> rowptr,
// counting-sort (c,v) into LDS staging, stream spack out coalesced.
// Replaces hist/block_sum/scan_final/scatter and all global atomics.
__global__ __launch_bounds__(256) void bucket_sort_kernel(
    const Edge12* __restrict__ eb, const int* __restrict__ fineBase,
    int2* __restrict__ spack, int* __restrict__ rowptr, int n)
{
    __shared__ int  rowCnt[RPB];        // counts, then relative cursors
    __shared__ int  rowStart[RPB + 1];  // exclusive prefix
    __shared__ int  scanTmp[RPB];
    __shared__ int  winEnd;
    __shared__ int2 st[CAP];            // 64 KB staging

    const int bkt = blockIdx.x;
    const int t   = threadIdx.x;
    const int lo  = fineBase[bkt];
    const int hi  = fineBase[bkt + 1];
    const int r0  = bkt << 8;

    rowCnt[t] = 0;
    __syncthreads();
    for (int e = lo + t; e < hi; e += 256)
        atomicAdd(&rowCnt[eb[e].r - r0], 1);
    __syncthreads();

    // exclusive scan over 256 row counts
    int v = rowCnt[t];
    scanTmp[t] = v;
    __syncthreads();
    for (int off = 1; off < 256; off <<= 1) {
        int x = (t >= off) ? scanTmp[t - off] : 0;
        __syncthreads();
        scanTmp[t] += x;
        __syncthreads();
    }
    rowStart[t + 1] = scanTmp[t];
    if (t == 0) rowStart[0] = 0;
    __syncthreads();

    // rowptr for this bucket's rows (coalesced)
    if (r0 + t < n) rowptr[r0 + t] = lo + rowStart[t];

    // windowed counting sort (single window in the common case)
    int rs = 0;
    while (rs < RPB) {
        if (t == 0) {
            int base = rowStart[rs];
            if (rowStart[rs + 1] - base > CAP) {
                winEnd = -(rs + 1);               // single row overflows CAP
            } else {
                int re = rs;
                while (re < RPB && rowStart[re + 1] - base <= CAP) ++re;
                winEnd = re;
            }
        }
        __syncthreads();
        int  re     = winEnd;
        bool direct = false;
        if (re < 0) { re = -re; direct = true; }
        const int base = rowStart[rs];
        const int cnt  = rowStart[re] - base;

        if (t >= rs && t < re) rowCnt[t] = rowStart[t] - base;
        __syncthreads();

        if (!direct) {
            for (int e = lo + t; e < hi; e += 256) {
                Edge12 ed = eb[e];
                int rl = ed.r - r0;
                if (rl >= rs && rl < re) {
                    int p = atomicAdd(&rowCnt[rl], 1);
                    st[p] = make_int2(ed.c, __float_as_int(ed.v));
                }
            }
            __syncthreads();
            for (int i = t; i < cnt; i += 256)
                spack[lo + base + i] = st[i];
        } else {
            // pathological single-row window: write direct (rare, correct)
            for (int e = lo + t; e < hi; e += 256) {
                Edge12 ed = eb[e];
                if (ed.r - r0 == rs) {
                    int p = atomicAdd(&rowCnt[rs], 1);
                    spack[lo + base + p] = make_int2(ed.c, __float_as_int(ed.v));
                }
            }
        }
        __syncthreads();
        rs = re;
    }
}

// ---------------------------------------------------------------------------
// CSR SpMM hop (unchanged): one wave per row, quarter-wave per edge.
// ---------------------------------------------------------------------------
template<bool DST_F32>
__global__ __launch_bounds__(256) void spmm_csr_kernel(
    const int* __restrict__ rowptr, const int2* __restrict__ spack,
    const unsigned short* __restrict__ src, void* __restrict__ dstv, int n)
{
    const int row  = blockIdx.x * 4 + (threadIdx.x >> 6);
    const int lane = threadIdx.x & 63;
    if (row >= n) return;

    const int beg = rowptr[row];
    const int end = rowptr[row + 1];
    const int sub = lane >> 4;
    const int ch  = (lane & 15) * 4;

    float4 acc0 = make_float4(0.f, 0.f, 0.f, 0.f);
    float4 acc1 = make_float4(0.f, 0.f, 0.f, 0.f);

    for (int b = beg; b < end; b += 16) {
        int e0 = b + sub;
        int e1 = b + 4 + sub;
        int e2 = b + 8 + sub;
        int e3 = b + 12 + sub;
        int2 p0 = spack[min(e0, end - 1)];
        int2 p1 = spack[min(e1, end - 1)];
        int2 p2 = spack[min(e2, end - 1)];
        int2 p3 = spack[min(e3, end - 1)];
        float v0 = (e0 < end) ? __int_as_float(p0.y) : 0.f;
        float v1 = (e1 < end) ? __int_as_float(p1.y) : 0.f;
        float v2 = (e2 < end) ? __int_as_float(p2.y) : 0.f;
        float v3 = (e3 < end) ? __int_as_float(p3.y) : 0.f;
        ushort4 s0 = *(const ushort4*)(src + ((size_t)p0.x << 6) + ch);
        ushort4 s1 = *(const ushort4*)(src + ((size_t)p1.x << 6) + ch);
        ushort4 s2 = *(const ushort4*)(src + ((size_t)p2.x << 6) + ch);
        ushort4 s3 = *(const ushort4*)(src + ((size_t)p3.x << 6) + ch);
        acc0.x = fmaf(v0, bf2f(s0.x), acc0.x);
        acc0.y = fmaf(v0, bf2f(s0.y), acc0.y);
        acc0.z = fmaf(v0, bf2f(s0.z), acc0.z);
        acc0.w = fmaf(v0, bf2f(s0.w), acc0.w);
        acc1.x = fmaf(v1, bf2f(s1.x), acc1.x);
        acc1.y = fmaf(v1, bf2f(s1.y), acc1.y);
        acc1.z = fmaf(v1, bf2f(s1.z), acc1.z);
        acc1.w = fmaf(v1, bf2f(s1.w), acc1.w);
        acc0.x = fmaf(v2, bf2f(s2.x), acc0.x);
        acc0.y = fmaf(v2, bf2f(s2.y), acc0.y);
        acc0.z = fmaf(v2, bf2f(s2.z), acc0.z);
        acc0.w = fmaf(v2, bf2f(s2.w), acc0.w);
        acc1.x = fmaf(v3, bf2f(s3.x), acc1.x);
        acc1.y = fmaf(v3, bf2f(s3.y), acc1.y);
        acc1.z = fmaf(v3, bf2f(s3.z), acc1.z);
        acc1.w = fmaf(v3, bf2f(s3.w), acc1.w);
    }

    float4 acc = make_float4(acc0.x + acc1.x, acc0.y + acc1.y,
                             acc0.z + acc1.z, acc0.w + acc1.w);

#pragma unroll
    for (int mask = 16; mask <= 32; mask <<= 1) {
        acc.x += __shfl_xor(acc.x, mask);
        acc.y += __shfl_xor(acc.y, mask);
        acc.z += __shfl_xor(acc.z, mask);
        acc.w += __shfl_xor(acc.w, mask);
    }

    if (lane < 16) {
        if constexpr (DST_F32) {
            *(float4*)((float*)dstv + ((size_t)row << 6) + ch) = acc;
        } else {
            ushort4 o;
            o.x = f2bf(acc.x);
            o.y = f2bf(acc.y);
            o.z = f2bf(acc.z);
            o.w = f2bf(acc.w);
            *(ushort4*)((unsigned short*)dstv + ((size_t)row << 6) + ch) = o;
        }
    }
}

// ---------------------------------------------------------------------------
extern "C" void kernel_launch(void* const* d_in, const int* in_sizes, int n_in,
                              void* d_out, int out_size, void* d_ws, size_t ws_size,
                              hipStream_t stream)
{
    const int*   adj  = (const int*)d_in[0];    // [2, E] int32
    const float* vals = (const float*)d_in[1];  // [E]
    const float* feat = (const float*)d_in[2];  // [N, 256]
    const float* W    = (const float*)d_in[3];  // [256, 64]
    const float* bias = (const float*)d_in[4];  // [1, 64]

    const int E = in_sizes[1];
    const int n = in_sizes[2] / IN_CH;
    const int* rows = adj;       // destination rows
    const int* cols = adj + E;   // gather sources

    const int nfine = (n + RPB - 1) >> 8;   // fine buckets of 256 rows

    // ---- workspace layout (256 B aligned regions) ----
    char* ws = (char*)d_ws;
    size_t off = 0;
    auto alloc = [&](size_t bytes) {
        void* p = ws + off;
        off += (bytes + 255) & ~(size_t)255;
        return p;
    };
    unsigned short* B0 = (unsigned short*)alloc((size_t)n * OUT_CH * sizeof(unsigned short));
    unsigned short* B1 = (unsigned short*)alloc((size_t)n * OUT_CH * sizeof(unsigned short));
    int*   rowptr      = (int*)  alloc((size_t)(n + 1) * sizeof(int));
    int2*  spack       = (int2*) alloc((size_t)E * sizeof(int2));
    int*   fineCnt     = (int*)  alloc(NFMAX * sizeof(int));
    int*   fineBase    = (int*)  alloc((NFMAX + 1) * sizeof(int));
    int*   flushCursor = (int*)  alloc(NFMAX * sizeof(int));

    // packed edge records alias B0+B1 (dead until gemm, which is
    // stream-ordered after bucket_sort): E*12 = 19.2 MB <= 25.6 MB.
    Edge12* eb = (Edge12*)B0;

    float* out = (float*)d_out;

    // ---- build CSR (LDS-staged counting sort) ----
    hipMemsetAsync(fineCnt, 0, (size_t)nfine * sizeof(int), stream);
    fine_count_kernel<<<256, 256, 0, stream>>>(rows, fineCnt, E, nfine);
    fine_scan_kernel<<<1, 256, 0, stream>>>(fineCnt, fineBase, flushCursor,
                                            rowptr, n, nfine, E);
    fine_scatter_kernel<<<(E + CHUNK - 1) / CHUNK, 256, 0, stream>>>(
        rows, cols, vals, flushCursor, eb, E, nfine);
    bucket_sort_kernel<<<nfine, 256, 0, stream>>>(eb, fineBase, spack, rowptr, n);

    // ---- dense transform (MFMA, bf16 output) ----
    gemm_mfma_kernel<<<(n + 63) / 64, 256, 0, stream>>>(feat, W, bias, B0, n);

    // ---- 3 SpMM hops: B0 -> B1 -> B0 -> out(fp32) ----
    const int hblocks = (n + 3) / 4;
    spmm_csr_kernel<false><<<hblocks, 256, 0, stream>>>(rowptr, spack, B0, B1, n);
    spmm_csr_kernel<false><<<hblocks, 256, 0, stream>>>(rowptr, spack, B1, B0, n);
    spmm_csr_kernel<true><<<hblocks, 256, 0, stream>>>(rowptr, spack, B0, out, n);
}

// Round 3
// 390.712 us; speedup vs baseline: 1.3227x; 1.0139x over previous
//
#include <hip/hip_runtime.h>
#include <hip/hip_bf16.h>

#define IN_CH 256
#define OUT_CH 64
#define NFMAX 512          // max fine buckets (n <= 131072)
#define RPB 256            // rows per fine bucket (b = r >> 8)
#define CHUNK 6144         // edges per fine_scatter block (24 per thread)
#define CAP 8192           // staged edges per bucket_sort window (64 KB LDS)

// ---- bf16 helpers ----
__device__ __forceinline__ unsigned short f2bf(float f) {   // manual RNE (prep paths)
    unsigned u = __float_as_uint(f);
    u += 0x7fff + ((u >> 16) & 1);
    return (unsigned short)(u >> 16);
}
__device__ __forceinline__ unsigned short f2bf_hw(float f) { // HW cvt (compiler pairs into v_cvt_pk_bf16_f32)
    __hip_bfloat16 h = __float2bfloat16(f);
    union { __hip_bfloat16 b; unsigned short u; } c;
    c.b = h;
    return c.u;
}
__device__ __forceinline__ float bf2f(unsigned short h) {
    return __uint_as_float((unsigned)h << 16);
}

struct Edge12 { int r; int c; float v; };   // packed 12 B edge record

using bfrag = __attribute__((ext_vector_type(8))) short;   // 8 bf16 (4 VGPRs)
using ffrag = __attribute__((ext_vector_type(4))) float;   // 4 fp32 acc

// ---------------------------------------------------------------------------
// W pre-convert: fragment-major bf16 Wf (32 KB), written once.
// Fragment read in gemm is then base + lane*16 B -> coalesced global dwordx4,
// L1/L2-resident. Kills per-block LDS staging + bank conflicts + occupancy cap.
// Layout: Wf[(((ks*4+nt)*64) + quad*16 + lc)*8 + j] = bf16(W[ks*32+quad*8+j][nt*16+lc])
// ---------------------------------------------------------------------------
__global__ __launch_bounds__(256) void wprep_kernel(
    const float* __restrict__ W, unsigned short* __restrict__ Wf)
{
    int i = blockIdx.x * 256 + threadIdx.x;   // 64 blocks x 256 = 16384
    int k  = i >> 6;
    int c  = i & 63;
    int ks = k >> 5;
    int kq = (k >> 3) & 3;
    int j  = k & 7;
    int nt = c >> 4;
    int lc = c & 15;
    Wf[(((ks * 4 + nt) * 64) + kq * 16 + lc) * 8 + j] = f2bf(W[i]);
}

// ---------------------------------------------------------------------------
// MFMA dense transform v2: no LDS. 128 rows/block, 32 rows/wave (2 groups).
// B-fragments read directly from fragment-major Wf (global, cache-resident).
// A converted with HW bf16 converts.
// ---------------------------------------------------------------------------
__global__ __launch_bounds__(256) void gemm_mfma_kernel(
    const float* __restrict__ feat, const unsigned short* __restrict__ Wf,
    const float* __restrict__ bias, unsigned short* __restrict__ out, int n)
{
    const int wv   = threadIdx.x >> 6;
    const int lane = threadIdx.x & 63;
    const int quad = lane >> 4;
    const int lc   = lane & 15;

    const int rbase = blockIdx.x * 128 + wv * 32;
    const int lrow0 = min(rbase + lc,      n - 1);
    const int lrow1 = min(rbase + 16 + lc, n - 1);
    const float4* frow0 = (const float4*)(feat + (size_t)lrow0 * IN_CH);
    const float4* frow1 = (const float4*)(feat + (size_t)lrow1 * IN_CH);

    ffrag acc0[4], acc1[4];
#pragma unroll
    for (int nt = 0; nt < 4; ++nt)
#pragma unroll
        for (int r = 0; r < 4; ++r) { acc0[nt][r] = 0.f; acc1[nt][r] = 0.f; }

#pragma unroll
    for (int ks = 0; ks < 8; ++ks) {
        float4 a00 = frow0[ks * 8 + quad * 2 + 0];
        float4 a01 = frow0[ks * 8 + quad * 2 + 1];
        float4 a10 = frow1[ks * 8 + quad * 2 + 0];
        float4 a11 = frow1[ks * 8 + quad * 2 + 1];
        bfrag af0, af1;
        af0[0] = (short)f2bf_hw(a00.x); af0[1] = (short)f2bf_hw(a00.y);
        af0[2] = (short)f2bf_hw(a00.z); af0[3] = (short)f2bf_hw(a00.w);
        af0[4] = (short)f2bf_hw(a01.x); af0[5] = (short)f2bf_hw(a01.y);
        af0[6] = (short)f2bf_hw(a01.z); af0[7] = (short)f2bf_hw(a01.w);
        af1[0] = (short)f2bf_hw(a10.x); af1[1] = (short)f2bf_hw(a10.y);
        af1[2] = (short)f2bf_hw(a10.z); af1[3] = (short)f2bf_hw(a10.w);
        af1[4] = (short)f2bf_hw(a11.x); af1[5] = (short)f2bf_hw(a11.y);
        af1[6] = (short)f2bf_hw(a11.z); af1[7] = (short)f2bf_hw(a11.w);
#pragma unroll
        for (int nt = 0; nt < 4; ++nt) {
            bfrag bf = *(const bfrag*)&Wf[(((ks * 4 + nt) * 64) + lane) * 8];
            acc0[nt] = __builtin_amdgcn_mfma_f32_16x16x32_bf16(af0, bf, acc0[nt], 0, 0, 0);
            acc1[nt] = __builtin_amdgcn_mfma_f32_16x16x32_bf16(af1, bf, acc1[nt], 0, 0, 0);
        }
    }

    // epilogue: bias + relu + bf16 store. C/D: row=quad*4+r, col=lane&15.
#pragma unroll
    for (int nt = 0; nt < 4; ++nt) {
        float bv = bias[nt * 16 + lc];
#pragma unroll
        for (int r = 0; r < 4; ++r) {
            int orow0 = rbase + quad * 4 + r;
            int orow1 = rbase + 16 + quad * 4 + r;
            if (orow0 < n) {
                float v = fmaxf(acc0[nt][r] + bv, 0.f);
                out[(size_t)orow0 * OUT_CH + nt * 16 + lc] = f2bf_hw(v);
            }
            if (orow1 < n) {
                float v = fmaxf(acc1[nt][r] + bv, 0.f);
                out[(size_t)orow1 * OUT_CH + nt * 16 + lc] = f2bf_hw(v);
            }
        }
    }
}

// ---------------------------------------------------------------------------
// CSR build v3 (unchanged from round 2): LDS-staged counting sort; all global
// writes are contiguous segments.
// ---------------------------------------------------------------------------
__global__ __launch_bounds__(256) void fine_count_kernel(
    const int* __restrict__ rows, int* __restrict__ fineCnt,
    int nEdges, int nfine)
{
    __shared__ int h[NFMAX];
    const int t = threadIdx.x;
    for (int i = t; i < nfine; i += 256) h[i] = 0;
    __syncthreads();
    const int stride = gridDim.x * 256;
    for (int e = blockIdx.x * 256 + t; e < nEdges; e += stride)
        atomicAdd(&h[__builtin_nontemporal_load(rows + e) >> 8], 1);
    __syncthreads();
    for (int i = t; i < nfine; i += 256) {
        int v = h[i];
        if (v) atomicAdd(&fineCnt[i], v);
    }
}

__global__ __launch_bounds__(256) void fine_scan_kernel(
    const int* __restrict__ fineCnt, int* __restrict__ fineBase,
    int* __restrict__ flushCursor, int* __restrict__ rowptr,
    int n, int nfine, int E)
{
    __shared__ int tmp[256];
    const int t = threadIdx.x;
    int a = (2 * t     < nfine) ? fineCnt[2 * t]     : 0;
    int b = (2 * t + 1 < nfine) ? fineCnt[2 * t + 1] : 0;
    tmp[t] = a + b;
    __syncthreads();
    for (int off = 1; off < 256; off <<= 1) {
        int x = (t >= off) ? tmp[t - off] : 0;
        __syncthreads();
        tmp[t] += x;
        __syncthreads();
    }
    int excl = tmp[t] - (a + b);
    if (2 * t < nfine)     { fineBase[2 * t]     = excl;     flushCursor[2 * t]     = excl;     }
    if (2 * t + 1 < nfine) { fineBase[2 * t + 1] = excl + a; flushCursor[2 * t + 1] = excl + a; }
    if (t == 0) { fineBase[nfine] = E; rowptr[n] = E; }
}

__global__ __launch_bounds__(256) void fine_scatter_kernel(
    const int* __restrict__ rows, const int* __restrict__ cols,
    const float* __restrict__ vals, int* __restrict__ flushCursor,
    Edge12* __restrict__ eb, int nEdges, int nfine)
{
    __shared__ int hist[NFMAX];
    __shared__ int lofs[NFMAX];
    __shared__ int gpos[NFMAX];
    __shared__ int cur[NFMAX];
    __shared__ int scanTmp[256];
    __shared__ int   sr[CHUNK];
    __shared__ int   sc[CHUNK];
    __shared__ float sv[CHUNK];

    const int t  = threadIdx.x;
    const int e0 = blockIdx.x * CHUNK;
    const int cnt_in = min(CHUNK, nEdges - e0);

    for (int i = t; i < nfine; i += 256) hist[i] = 0;
    __syncthreads();

    int   lr[CHUNK / 256];
    int   lc[CHUNK / 256];
    float lv[CHUNK / 256];
#pragma unroll
    for (int j = 0; j < CHUNK / 256; ++j) {
        int i = j * 256 + t;
        if (i < cnt_in) {
            lr[j] = __builtin_nontemporal_load(rows + e0 + i);
            lc[j] = __builtin_nontemporal_load(cols + e0 + i);
            lv[j] = __builtin_nontemporal_load(vals + e0 + i);
            atomicAdd(&hist[lr[j] >> 8], 1);
        } else {
            lr[j] = -1;
        }
    }
    __syncthreads();

    int a  = (2 * t     < nfine) ? hist[2 * t]     : 0;
    int b2 = (2 * t + 1 < nfine) ? hist[2 * t + 1] : 0;
    scanTmp[t] = a + b2;
    __syncthreads();
    for (int off = 1; off < 256; off <<= 1) {
        int x = (t >= off) ? scanTmp[t - off] : 0;
        __syncthreads();
        scanTmp[t] += x;
        __syncthreads();
    }
    int excl = scanTmp[t] - (a + b2);
    if (2 * t < nfine)     lofs[2 * t]     = excl;
    if (2 * t + 1 < nfine) lofs[2 * t + 1] = excl + a;
    __syncthreads();

    for (int i = t; i < nfine; i += 256) {
        int h = hist[i];
        gpos[i] = h ? atomicAdd(&flushCursor[i], h) : 0;
        cur[i]  = lofs[i];
    }
    __syncthreads();

#pragma unroll
    for (int j = 0; j < CHUNK / 256; ++j) {
        if (lr[j] >= 0) {
            int bk = lr[j] >> 8;
            int p  = atomicAdd(&cur[bk], 1);
            sr[p] = lr[j];
            sc[p] = lc[j];
            sv[p] = lv[j];
        }
    }
    __syncthreads();

    for (int i = t; i < cnt_in; i += 256) {
        int bk = sr[i] >> 8;
        int p  = gpos[bk] + (i - lofs[bk]);
        eb[p].r = sr[i];
        eb[p].c = sc[i];
        eb[p].v = sv[i];
    }
}

__global__ __launch_bounds__(256) void bucket_sort_kernel(
    const Edge12* __restrict__ eb, const int* __restrict__ fineBase,
    int2* __restrict__ spack, int* __restrict__ rowptr, int n)
{
    __shared__ int  rowCnt[RPB];
    __shared__ int  rowStart[RPB + 1];
    __shared__ int  scanTmp[RPB];
    __shared__ int  winEnd;
    __shared__ int2 st[CAP];            // 64 KB staging

    const int bkt = blockIdx.x;
    const int t   = threadIdx.x;
    const int lo  = fineBase[bkt];
    const int hi  = fineBase[bkt + 1];
    const int r0  = bkt << 8;

    rowCnt[t] = 0;
    __syncthreads();
    for (int e = lo + t; e < hi; e += 256)
        atomicAdd(&rowCnt[eb[e].r - r0], 1);
    __syncthreads();

    int v = rowCnt[t];
    scanTmp[t] = v;
    __syncthreads();
    for (int off = 1; off < 256; off <<= 1) {
        int x = (t >= off) ? scanTmp[t - off] : 0;
        __syncthreads();
        scanTmp[t] += x;
        __syncthreads();
    }
    rowStart[t + 1] = scanTmp[t];
    if (t == 0) rowStart[0] = 0;
    __syncthreads();

    if (r0 + t < n) rowptr[r0 + t] = lo + rowStart[t];

    int rs = 0;
    while (rs < RPB) {
        if (t == 0) {
            int base = rowStart[rs];
            if (rowStart[rs + 1] - base > CAP) {
                winEnd = -(rs + 1);
            } else {
                int re = rs;
                while (re < RPB && rowStart[re + 1] - base <= CAP) ++re;
                winEnd = re;
            }
        }
        __syncthreads();
        int  re     = winEnd;
        bool direct = false;
        if (re < 0) { re = -re; direct = true; }
        const int base = rowStart[rs];
        const int cnt  = rowStart[re] - base;

        if (t >= rs && t < re) rowCnt[t] = rowStart[t] - base;
        __syncthreads();

        if (!direct) {
            for (int e = lo + t; e < hi; e += 256) {
                Edge12 ed = eb[e];
                int rl = ed.r - r0;
                if (rl >= rs && rl < re) {
                    int p = atomicAdd(&rowCnt[rl], 1);
                    st[p] = make_int2(ed.c, __float_as_int(ed.v));
                }
            }
            __syncthreads();
            for (int i = t; i < cnt; i += 256)
                spack[lo + base + i] = st[i];
        } else {
            for (int e = lo + t; e < hi; e += 256) {
                Edge12 ed = eb[e];
                if (ed.r - r0 == rs) {
                    int p = atomicAdd(&rowCnt[rs], 1);
                    spack[lo + base + p] = make_int2(ed.c, __float_as_int(ed.v));
                }
            }
        }
        __syncthreads();
        rs = re;
    }
}

// ---------------------------------------------------------------------------
// CSR SpMM hop (unchanged): one wave per row, quarter-wave per edge.
// ---------------------------------------------------------------------------
template<bool DST_F32>
__global__ __launch_bounds__(256) void spmm_csr_kernel(
    const int* __restrict__ rowptr, const int2* __restrict__ spack,
    const unsigned short* __restrict__ src, void* __restrict__ dstv, int n)
{
    const int row  = blockIdx.x * 4 + (threadIdx.x >> 6);
    const int lane = threadIdx.x & 63;
    if (row >= n) return;

    const int beg = rowptr[row];
    const int end = rowptr[row + 1];
    const int sub = lane >> 4;
    const int ch  = (lane & 15) * 4;

    float4 acc0 = make_float4(0.f, 0.f, 0.f, 0.f);
    float4 acc1 = make_float4(0.f, 0.f, 0.f, 0.f);

    for (int b = beg; b < end; b += 16) {
        int e0 = b + sub;
        int e1 = b + 4 + sub;
        int e2 = b + 8 + sub;
        int e3 = b + 12 + sub;
        int2 p0 = spack[min(e0, end - 1)];
        int2 p1 = spack[min(e1, end - 1)];
        int2 p2 = spack[min(e2, end - 1)];
        int2 p3 = spack[min(e3, end - 1)];
        float v0 = (e0 < end) ? __int_as_float(p0.y) : 0.f;
        float v1 = (e1 < end) ? __int_as_float(p1.y) : 0.f;
        float v2 = (e2 < end) ? __int_as_float(p2.y) : 0.f;
        float v3 = (e3 < end) ? __int_as_float(p3.y) : 0.f;
        ushort4 s0 = *(const ushort4*)(src + ((size_t)p0.x << 6) + ch);
        ushort4 s1 = *(const ushort4*)(src + ((size_t)p1.x << 6) + ch);
        ushort4 s2 = *(const ushort4*)(src + ((size_t)p2.x << 6) + ch);
        ushort4 s3 = *(const ushort4*)(src + ((size_t)p3.x << 6) + ch);
        acc0.x = fmaf(v0, bf2f(s0.x), acc0.x);
        acc0.y = fmaf(v0, bf2f(s0.y), acc0.y);
        acc0.z = fmaf(v0, bf2f(s0.z), acc0.z);
        acc0.w = fmaf(v0, bf2f(s0.w), acc0.w);
        acc1.x = fmaf(v1, bf2f(s1.x), acc1.x);
        acc1.y = fmaf(v1, bf2f(s1.y), acc1.y);
        acc1.z = fmaf(v1, bf2f(s1.z), acc1.z);
        acc1.w = fmaf(v1, bf2f(s1.w), acc1.w);
        acc0.x = fmaf(v2, bf2f(s2.x), acc0.x);
        acc0.y = fmaf(v2, bf2f(s2.y), acc0.y);
        acc0.z = fmaf(v2, bf2f(s2.z), acc0.z);
        acc0.w = fmaf(v2, bf2f(s2.w), acc0.w);
        acc1.x = fmaf(v3, bf2f(s3.x), acc1.x);
        acc1.y = fmaf(v3, bf2f(s3.y), acc1.y);
        acc1.z = fmaf(v3, bf2f(s3.z), acc1.z);
        acc1.w = fmaf(v3, bf2f(s3.w), acc1.w);
    }

    float4 acc = make_float4(acc0.x + acc1.x, acc0.y + acc1.y,
                             acc0.z + acc1.z, acc0.w + acc1.w);

#pragma unroll
    for (int mask = 16; mask <= 32; mask <<= 1) {
        acc.x += __shfl_xor(acc.x, mask);
        acc.y += __shfl_xor(acc.y, mask);
        acc.z += __shfl_xor(acc.z, mask);
        acc.w += __shfl_xor(acc.w, mask);
    }

    if (lane < 16) {
        if constexpr (DST_F32) {
            *(float4*)((float*)dstv + ((size_t)row << 6) + ch) = acc;
        } else {
            ushort4 o;
            o.x = f2bf_hw(acc.x);
            o.y = f2bf_hw(acc.y);
            o.z = f2bf_hw(acc.z);
            o.w = f2bf_hw(acc.w);
            *(ushort4*)((unsigned short*)dstv + ((size_t)row << 6) + ch) = o;
        }
    }
}

// ---------------------------------------------------------------------------
extern "C" void kernel_launch(void* const* d_in, const int* in_sizes, int n_in,
                              void* d_out, int out_size, void* d_ws, size_t ws_size,
                              hipStream_t stream)
{
    const int*   adj  = (const int*)d_in[0];    // [2, E] int32
    const float* vals = (const float*)d_in[1];  // [E]
    const float* feat = (const float*)d_in[2];  // [N, 256]
    const float* W    = (const float*)d_in[3];  // [256, 64]
    const float* bias = (const float*)d_in[4];  // [1, 64]

    const int E = in_sizes[1];
    const int n = in_sizes[2] / IN_CH;
    const int* rows = adj;       // destination rows
    const int* cols = adj + E;   // gather sources

    const int nfine = (n + RPB - 1) >> 8;   // fine buckets of 256 rows

    // ---- workspace layout (256 B aligned regions) ----
    char* ws = (char*)d_ws;
    size_t off = 0;
    auto alloc = [&](size_t bytes) {
        void* p = ws + off;
        off += (bytes + 255) & ~(size_t)255;
        return p;
    };
    unsigned short* B0 = (unsigned short*)alloc((size_t)n * OUT_CH * sizeof(unsigned short));
    unsigned short* B1 = (unsigned short*)alloc((size_t)n * OUT_CH * sizeof(unsigned short));
    int*   rowptr      = (int*)  alloc((size_t)(n + 1) * sizeof(int));
    int2*  spack       = (int2*) alloc((size_t)E * sizeof(int2));
    int*   fineCnt     = (int*)  alloc(NFMAX * sizeof(int));
    int*   fineBase    = (int*)  alloc((NFMAX + 1) * sizeof(int));
    int*   flushCursor = (int*)  alloc(NFMAX * sizeof(int));
    unsigned short* Wf = (unsigned short*)alloc((size_t)IN_CH * OUT_CH * sizeof(unsigned short));

    // packed edge records alias B0+B1 (dead until gemm, which is
    // stream-ordered after bucket_sort): E*12 = 19.2 MB <= 25.6 MB.
    Edge12* eb = (Edge12*)B0;

    float* out = (float*)d_out;

    // ---- W pre-convert (independent, tiny) ----
    wprep_kernel<<<(IN_CH * OUT_CH) / 256, 256, 0, stream>>>(W, Wf);

    // ---- build CSR (LDS-staged counting sort) ----
    hipMemsetAsync(fineCnt, 0, (size_t)nfine * sizeof(int), stream);
    fine_count_kernel<<<256, 256, 0, stream>>>(rows, fineCnt, E, nfine);
    fine_scan_kernel<<<1, 256, 0, stream>>>(fineCnt, fineBase, flushCursor,
                                            rowptr, n, nfine, E);
    fine_scatter_kernel<<<(E + CHUNK - 1) / CHUNK, 256, 0, stream>>>(
        rows, cols, vals, flushCursor, eb, E, nfine);
    bucket_sort_kernel<<<nfine, 256, 0, stream>>>(eb, fineBase, spack, rowptr, n);

    // ---- dense transform (MFMA, bf16 output, no LDS) ----
    gemm_mfma_kernel<<<(n + 127) / 128, 256, 0, stream>>>(feat, Wf, bias, B0, n);

    // ---- 3 SpMM hops: B0 -> B1 -> B0 -> out(fp32) ----
    const int hblocks = (n + 3) / 4;
    spmm_csr_kernel<false><<<hblocks, 256, 0, stream>>>(rowptr, spack, B0, B1, n);
    spmm_csr_kernel<false><<<hblocks, 256, 0, stream>>>(rowptr, spack, B1, B0, n);
    spmm_csr_kernel<true><<<hblocks, 256, 0, stream>>>(rowptr, spack, B0, out, n);
}

// Round 4
// 372.849 us; speedup vs baseline: 1.3861x; 1.0479x over previous
//
#include <hip/hip_runtime.h>
#include <hip/hip_bf16.h>

#define IN_CH 256
#define OUT_CH 64
#define NFMAX 512          // max fine buckets (n <= 131072)
#define RPB 256            // rows per fine bucket (b = r >> 8)
#define CHUNK 6144         // edges per fine_scatter block (24 per thread)
#define CAP 8192           // staged edges per bucket_sort window (64 KB LDS)

// ---- bf16 helpers ----
__device__ __forceinline__ unsigned short f2bf(float f) {   // manual RNE (prep paths)
    unsigned u = __float_as_uint(f);
    u += 0x7fff + ((u >> 16) & 1);
    return (unsigned short)(u >> 16);
}
__device__ __forceinline__ unsigned short f2bf_hw(float f) { // HW cvt (pairs into v_cvt_pk_bf16_f32)
    __hip_bfloat16 h = __float2bfloat16(f);
    union { __hip_bfloat16 b; unsigned short u; } c;
    c.b = h;
    return c.u;
}
__device__ __forceinline__ float bf2f(unsigned short h) {
    return __uint_as_float((unsigned)h << 16);
}

using bfrag = __attribute__((ext_vector_type(8))) short;   // 8 bf16 (4 VGPRs)
using ffrag = __attribute__((ext_vector_type(4))) float;   // 4 fp32 acc
using f32x4 = __attribute__((ext_vector_type(4))) float;   // vector type for NT loads

// ---------------------------------------------------------------------------
// W pre-convert: fragment-major bf16 Wf (32 KB), written once.
// ---------------------------------------------------------------------------
__global__ __launch_bounds__(256) void wprep_kernel(
    const float* __restrict__ W, unsigned short* __restrict__ Wf)
{
    int i = blockIdx.x * 256 + threadIdx.x;   // 64 blocks x 256 = 16384
    int k  = i >> 6;
    int c  = i & 63;
    int ks = k >> 5;
    int kq = (k >> 3) & 3;
    int j  = k & 7;
    int nt = c >> 4;
    int lc = c & 15;
    Wf[(((ks * 4 + nt) * 64) + kq * 16 + lc) * 8 + j] = f2bf(W[i]);
}

// ---------------------------------------------------------------------------
// MFMA dense transform v4: 16 rows/wave, FULL row prefetch (16 x 16 B NT
// loads in flight before any convert/MFMA) -> MLP-limited streaming fix.
// NT on feat keeps the 32 KB Wf resident in L1.
// ---------------------------------------------------------------------------
__global__ __launch_bounds__(256) void gemm_mfma_kernel(
    const float* __restrict__ feat, const unsigned short* __restrict__ Wf,
    const float* __restrict__ bias, unsigned short* __restrict__ out, int n)
{
    const int wv   = threadIdx.x >> 6;
    const int lane = threadIdx.x & 63;
    const int quad = lane >> 4;
    const int lc   = lane & 15;

    const int rbase = blockIdx.x * 64 + wv * 16;
    const int lrow  = min(rbase + lc, n - 1);
    const f32x4* frow = (const f32x4*)(feat + (size_t)lrow * IN_CH);

    // prefetch the whole 1 KB row slice for this lane: 16 independent loads
    f32x4 a[16];
#pragma unroll
    for (int i = 0; i < 16; ++i) {
        int ks = i >> 1;
        int j  = i & 1;
        a[i] = __builtin_nontemporal_load(frow + ks * 8 + quad * 2 + j);
    }

    ffrag acc[4];
#pragma unroll
    for (int nt = 0; nt < 4; ++nt)
#pragma unroll
        for (int r = 0; r < 4; ++r) acc[nt][r] = 0.f;

#pragma unroll
    for (int ks = 0; ks < 8; ++ks) {
        f32x4 a0 = a[ks * 2 + 0];
        f32x4 a1 = a[ks * 2 + 1];
        bfrag af;
        af[0] = (short)f2bf_hw(a0[0]); af[1] = (short)f2bf_hw(a0[1]);
        af[2] = (short)f2bf_hw(a0[2]); af[3] = (short)f2bf_hw(a0[3]);
        af[4] = (short)f2bf_hw(a1[0]); af[5] = (short)f2bf_hw(a1[1]);
        af[6] = (short)f2bf_hw(a1[2]); af[7] = (short)f2bf_hw(a1[3]);
#pragma unroll
        for (int nt = 0; nt < 4; ++nt) {
            bfrag bf = *(const bfrag*)&Wf[(((ks * 4 + nt) * 64) + lane) * 8];
            acc[nt] = __builtin_amdgcn_mfma_f32_16x16x32_bf16(af, bf, acc[nt], 0, 0, 0);
        }
    }

    // epilogue: bias + relu + bf16 store. C/D: row=quad*4+r, col=lane&15.
#pragma unroll
    for (int nt = 0; nt < 4; ++nt) {
        float bv = bias[nt * 16 + lc];
#pragma unroll
        for (int r = 0; r < 4; ++r) {
            int orow = rbase + quad * 4 + r;
            if (orow < n) {
                float v = fmaxf(acc[nt][r] + bv, 0.f);
                out[(size_t)orow * OUT_CH + nt * 16 + lc] = f2bf_hw(v);
            }
        }
    }
}

// ---------------------------------------------------------------------------
// CSR build v3.1: LDS-staged counting sort; all global writes contiguous.
// Edge records split SoA: ebcv (c,v int2) + ebr (in-bucket row, u8).
// ---------------------------------------------------------------------------
__global__ __launch_bounds__(256) void fine_count_kernel(
    const int* __restrict__ rows, int* __restrict__ fineCnt,
    int nEdges, int nfine)
{
    __shared__ int h[NFMAX];
    const int t = threadIdx.x;
    for (int i = t; i < nfine; i += 256) h[i] = 0;
    __syncthreads();
    const int stride = gridDim.x * 256;
    for (int e = blockIdx.x * 256 + t; e < nEdges; e += stride)
        atomicAdd(&h[__builtin_nontemporal_load(rows + e) >> 8], 1);
    __syncthreads();
    for (int i = t; i < nfine; i += 256) {
        int v = h[i];
        if (v) atomicAdd(&fineCnt[i], v);
    }
}

__global__ __launch_bounds__(256) void fine_scan_kernel(
    const int* __restrict__ fineCnt, int* __restrict__ fineBase,
    int* __restrict__ flushCursor, int* __restrict__ rowptr,
    int n, int nfine, int E)
{
    __shared__ int tmp[256];
    const int t = threadIdx.x;
    int a = (2 * t     < nfine) ? fineCnt[2 * t]     : 0;
    int b = (2 * t + 1 < nfine) ? fineCnt[2 * t + 1] : 0;
    tmp[t] = a + b;
    __syncthreads();
    for (int off = 1; off < 256; off <<= 1) {
        int x = (t >= off) ? tmp[t - off] : 0;
        __syncthreads();
        tmp[t] += x;
        __syncthreads();
    }
    int excl = tmp[t] - (a + b);
    if (2 * t < nfine)     { fineBase[2 * t]     = excl;     flushCursor[2 * t]     = excl;     }
    if (2 * t + 1 < nfine) { fineBase[2 * t + 1] = excl + a; flushCursor[2 * t + 1] = excl + a; }
    if (t == 0) { fineBase[nfine] = E; rowptr[n] = E; }
}

__global__ __launch_bounds__(256) void fine_scatter_kernel(
    const int* __restrict__ rows, const int* __restrict__ cols,
    const float* __restrict__ vals, int* __restrict__ flushCursor,
    int2* __restrict__ ebcv, unsigned char* __restrict__ ebr,
    int nEdges, int nfine)
{
    __shared__ int hist[NFMAX];
    __shared__ int lofs[NFMAX];
    __shared__ int gpos[NFMAX];
    __shared__ int cur[NFMAX];
    __shared__ int scanTmp[256];
    __shared__ int   sr[CHUNK];
    __shared__ int   sc[CHUNK];
    __shared__ float sv[CHUNK];

    const int t  = threadIdx.x;
    const int e0 = blockIdx.x * CHUNK;
    const int cnt_in = min(CHUNK, nEdges - e0);

    for (int i = t; i < nfine; i += 256) hist[i] = 0;
    __syncthreads();

    int   lr[CHUNK / 256];
    int   lc[CHUNK / 256];
    float lv[CHUNK / 256];
#pragma unroll
    for (int j = 0; j < CHUNK / 256; ++j) {
        int i = j * 256 + t;
        if (i < cnt_in) {
            lr[j] = __builtin_nontemporal_load(rows + e0 + i);
            lc[j] = __builtin_nontemporal_load(cols + e0 + i);
            lv[j] = __builtin_nontemporal_load(vals + e0 + i);
            atomicAdd(&hist[lr[j] >> 8], 1);
        } else {
            lr[j] = -1;
        }
    }
    __syncthreads();

    int a  = (2 * t     < nfine) ? hist[2 * t]     : 0;
    int b2 = (2 * t + 1 < nfine) ? hist[2 * t + 1] : 0;
    scanTmp[t] = a + b2;
    __syncthreads();
    for (int off = 1; off < 256; off <<= 1) {
        int x = (t >= off) ? scanTmp[t - off] : 0;
        __syncthreads();
        scanTmp[t] += x;
        __syncthreads();
    }
    int excl = scanTmp[t] - (a + b2);
    if (2 * t < nfine)     lofs[2 * t]     = excl;
    if (2 * t + 1 < nfine) lofs[2 * t + 1] = excl + a;
    __syncthreads();

    for (int i = t; i < nfine; i += 256) {
        int h = hist[i];
        gpos[i] = h ? atomicAdd(&flushCursor[i], h) : 0;
        cur[i]  = lofs[i];
    }
    __syncthreads();

#pragma unroll
    for (int j = 0; j < CHUNK / 256; ++j) {
        if (lr[j] >= 0) {
            int bk = lr[j] >> 8;
            int p  = atomicAdd(&cur[bk], 1);
            sr[p] = lr[j];
            sc[p] = lc[j];
            sv[p] = lv[j];
        }
    }
    __syncthreads();

    for (int i = t; i < cnt_in; i += 256) {
        int bk = sr[i] >> 8;
        int p  = gpos[bk] + (i - lofs[bk]);
        ebcv[p] = make_int2(sc[i], __float_as_int(sv[i]));
        ebr[p]  = (unsigned char)(sr[i] & 255);
    }
}

__global__ __launch_bounds__(256) void bucket_sort_kernel(
    const int2* __restrict__ ebcv, const unsigned char* __restrict__ ebr,
    const int* __restrict__ fineBase,
    int2* __restrict__ spack, int* __restrict__ rowptr, int n)
{
    __shared__ int  rowCnt[RPB];
    __shared__ int  rowStart[RPB + 1];
    __shared__ int  scanTmp[RPB];
    __shared__ int  winEnd;
    __shared__ int2 st[CAP];            // 64 KB staging

    const int bkt = blockIdx.x;
    const int t   = threadIdx.x;
    const int lo  = fineBase[bkt];
    const int hi  = fineBase[bkt + 1];
    const int r0  = bkt << 8;

    rowCnt[t] = 0;
    __syncthreads();
    for (int e = lo + t; e < hi; e += 256)
        atomicAdd(&rowCnt[ebr[e]], 1);
    __syncthreads();

    int v = rowCnt[t];
    scanTmp[t] = v;
    __syncthreads();
    for (int off = 1; off < 256; off <<= 1) {
        int x = (t >= off) ? scanTmp[t - off] : 0;
        __syncthreads();
        scanTmp[t] += x;
        __syncthreads();
    }
    rowStart[t + 1] = scanTmp[t];
    if (t == 0) rowStart[0] = 0;
    __syncthreads();

    if (r0 + t < n) rowptr[r0 + t] = lo + rowStart[t];

    int rs = 0;
    while (rs < RPB) {
        if (t == 0) {
            int base = rowStart[rs];
            if (rowStart[rs + 1] - base > CAP) {
                winEnd = -(rs + 1);
            } else {
                int re = rs;
                while (re < RPB && rowStart[re + 1] - base <= CAP) ++re;
                winEnd = re;
            }
        }
        __syncthreads();
        int  re     = winEnd;
        bool direct = false;
        if (re < 0) { re = -re; direct = true; }
        const int base = rowStart[rs];
        const int cnt  = rowStart[re] - base;

        if (t >= rs && t < re) rowCnt[t] = rowStart[t] - base;
        __syncthreads();

        if (!direct) {
            for (int e = lo + t; e < hi; e += 256) {
                int rl = ebr[e];
                if (rl >= rs && rl < re) {
                    int p = atomicAdd(&rowCnt[rl], 1);
                    st[p] = ebcv[e];
                }
            }
            __syncthreads();
            for (int i = t; i < cnt; i += 256)
                spack[lo + base + i] = st[i];
        } else {
            for (int e = lo + t; e < hi; e += 256) {
                int rl = ebr[e];
                if (rl == rs) {
                    int p = atomicAdd(&rowCnt[rs], 1);
                    spack[lo + base + p] = ebcv[e];
                }
            }
        }
        __syncthreads();
        rs = re;
    }
}

// ---------------------------------------------------------------------------
// CSR SpMM hop v2: one row per quarter-wave (4 rows/wave, 16 rows/block).
// No cross-lane reduce; 4 edges in flight per row; full-wave stores.
// ---------------------------------------------------------------------------
template<bool DST_F32>
__global__ __launch_bounds__(256) void spmm_csr_kernel(
    const int* __restrict__ rowptr, const int2* __restrict__ spack,
    const unsigned short* __restrict__ src, void* __restrict__ dstv, int n)
{
    const int wid  = threadIdx.x >> 6;
    const int lane = threadIdx.x & 63;
    const int sub  = lane >> 4;
    const int ch   = (lane & 15) * 4;
    const int row  = blockIdx.x * 16 + wid * 4 + sub;
    const bool valid = row < n;

    int beg = 0, end = 0;
    if (valid) { beg = rowptr[row]; end = rowptr[row + 1]; }

    float4 acc = make_float4(0.f, 0.f, 0.f, 0.f);

    for (int b = beg; b < end; b += 4) {
        int2  p[4];
        float v[4];
#pragma unroll
        for (int j = 0; j < 4; ++j) {
            int e = b + j;
            p[j] = spack[min(e, end - 1)];
            v[j] = (e < end) ? __int_as_float(p[j].y) : 0.f;
        }
        ushort4 s[4];
#pragma unroll
        for (int j = 0; j < 4; ++j)
            s[j] = *(const ushort4*)(src + ((size_t)p[j].x << 6) + ch);
#pragma unroll
        for (int j = 0; j < 4; ++j) {
            acc.x = fmaf(v[j], bf2f(s[j].x), acc.x);
            acc.y = fmaf(v[j], bf2f(s[j].y), acc.y);
            acc.z = fmaf(v[j], bf2f(s[j].z), acc.z);
            acc.w = fmaf(v[j], bf2f(s[j].w), acc.w);
        }
    }

    if (valid) {
        if constexpr (DST_F32) {
            *(float4*)((float*)dstv + ((size_t)row << 6) + ch) = acc;
        } else {
            ushort4 o;
            o.x = f2bf_hw(acc.x);
            o.y = f2bf_hw(acc.y);
            o.z = f2bf_hw(acc.z);
            o.w = f2bf_hw(acc.w);
            *(ushort4*)((unsigned short*)dstv + ((size_t)row << 6) + ch) = o;
        }
    }
}

// ---------------------------------------------------------------------------
extern "C" void kernel_launch(void* const* d_in, const int* in_sizes, int n_in,
                              void* d_out, int out_size, void* d_ws, size_t ws_size,
                              hipStream_t stream)
{
    const int*   adj  = (const int*)d_in[0];    // [2, E] int32
    const float* vals = (const float*)d_in[1];  // [E]
    const float* feat = (const float*)d_in[2];  // [N, 256]
    const float* W    = (const float*)d_in[3];  // [256, 64]
    const float* bias = (const float*)d_in[4];  // [1, 64]

    const int E = in_sizes[1];
    const int n = in_sizes[2] / IN_CH;
    const int* rows = adj;       // destination rows
    const int* cols = adj + E;   // gather sources

    const int nfine = (n + RPB - 1) >> 8;   // fine buckets of 256 rows

    // ---- workspace layout (256 B aligned regions) ----
    char* ws = (char*)d_ws;
    size_t off = 0;
    auto alloc = [&](size_t bytes) {
        void* p = ws + off;
        off += (bytes + 255) & ~(size_t)255;
        return p;
    };
    unsigned short* B0 = (unsigned short*)alloc((size_t)n * OUT_CH * sizeof(unsigned short));
    unsigned short* B1 = (unsigned short*)alloc((size_t)n * OUT_CH * sizeof(unsigned short));
    int*   rowptr      = (int*)  alloc((size_t)(n + 1) * sizeof(int));
    int2*  spack       = (int2*) alloc((size_t)E * sizeof(int2));
    int*   fineCnt     = (int*)  alloc(NFMAX * sizeof(int));
    int*   fineBase    = (int*)  alloc((NFMAX + 1) * sizeof(int));
    int*   flushCursor = (int*)  alloc(NFMAX * sizeof(int));
    unsigned short* Wf = (unsigned short*)alloc((size_t)IN_CH * OUT_CH * sizeof(unsigned short));

    // packed edge records alias B0+B1 (dead until gemm, stream-ordered after
    // bucket_sort): E*8 + E*1 = 14.4 MB <= 25.6 MB.
    int2*          ebcv = (int2*)B0;
    unsigned char* ebr  = (unsigned char*)(ebcv + E);

    float* out = (float*)d_out;

    // ---- W pre-convert (independent, tiny) ----
    wprep_kernel<<<(IN_CH * OUT_CH) / 256, 256, 0, stream>>>(W, Wf);

    // ---- build CSR (LDS-staged counting sort) ----
    hipMemsetAsync(fineCnt, 0, (size_t)nfine * sizeof(int), stream);
    fine_count_kernel<<<256, 256, 0, stream>>>(rows, fineCnt, E, nfine);
    fine_scan_kernel<<<1, 256, 0, stream>>>(fineCnt, fineBase, flushCursor,
                                            rowptr, n, nfine, E);
    fine_scatter_kernel<<<(E + CHUNK - 1) / CHUNK, 256, 0, stream>>>(
        rows, cols, vals, flushCursor, ebcv, ebr, E, nfine);
    bucket_sort_kernel<<<nfine, 256, 0, stream>>>(ebcv, ebr, fineBase,
                                                  spack, rowptr, n);

    // ---- dense transform (MFMA, bf16 output, full-row prefetch) ----
    gemm_mfma_kernel<<<(n + 63) / 64, 256, 0, stream>>>(feat, Wf, bias, B0, n);

    // ---- 3 SpMM hops: B0 -> B1 -> B0 -> out(fp32) ----
    const int hblocks = (n + 15) / 16;
    spmm_csr_kernel<false><<<hblocks, 256, 0, stream>>>(rowptr, spack, B0, B1, n);
    spmm_csr_kernel<false><<<hblocks, 256, 0, stream>>>(rowptr, spack, B1, B0, n);
    spmm_csr_kernel<true><<<hblocks, 256, 0, stream>>>(rowptr, spack, B0, out, n);
}